// Round 16
// baseline (42.509 us; speedup 1.0000x reference)
//
#include <hip/hip_runtime.h>
#include <math.h>

// Problem constants (fixed by setup_inputs)
#define BB 2
#define TT 5
#define NPTS 4096
#define NBT (BB * TT)
#define NELEM (BB * TT * 64 * 2048)   // 1,310,720

#define EW_BLOCKS 640                 // bids 0..639
// Chamfer: 2 dir x 10 bt x 64 qc = 1280 blocks (bids 640..1919), 64 queries each
#define CH_BLOCKS 1280
#define QPB 64
#define NQC 64
#define TOT_BLOCKS (EW_BLOCKS + CH_BLOCKS)   // 1920

// ws layout (floats):
//   [0..1280)      chamfer partials, slot = dir*640 + bt*64 + qc
//   [1280..1920)   ew srv partials
//   [1920..2560)   ew smk partials
//   [2560]         block-arrival counter (uint, monotonically grows across calls)
#define EW1 1280
#define EW2 1920
#define CNT_IDX 2560

typedef _Float16 h8 __attribute__((ext_vector_type(8)));
typedef float f32x16 __attribute__((ext_vector_type(16)));
typedef float f32x4 __attribute__((ext_vector_type(4)));

__device__ inline unsigned pkh(float a, float b) {
    union { _Float16 h[2]; unsigned u; } c;
    c.h[0] = (_Float16)a;          // RNE conversion (accuracy: 4.9e-4 measured)
    c.h[1] = (_Float16)b;
    return c.u;
}

__device__ inline void st_agent(float* p, float v) {
    __hip_atomic_store(p, v, __ATOMIC_RELAXED, __HIP_MEMORY_SCOPE_AGENT);
}
__device__ inline float ld_agent(const float* p) {
    return __hip_atomic_load(p, __ATOMIC_RELAXED, __HIP_MEMORY_SCOPE_AGENT);
}

__global__ __launch_bounds__(256) void main_kernel(
        const float4* __restrict__ rv4,
        const float4* __restrict__ lg4,
        const float4* __restrict__ tg4,
        const float* __restrict__ OP,
        const float* __restrict__ TP,
        float* __restrict__ ws,
        float* __restrict__ out) {
    __shared__ __align__(16) uint2 pts[4096];   // (x,y)f16,(z,n)f16 per point, 32 KB
    __shared__ float nqlds[64];
    __shared__ float qmin[2][64];
    __shared__ float s1[4], s2[4];
    __shared__ float grp[20];
    __shared__ float ra[4], rb[4];
    __shared__ unsigned lastf;
    int bid = blockIdx.x;
    int tid = threadIdx.x;
    int lane = tid & 63;
    int wave = tid >> 6;

    if (bid < EW_BLOCKS) {
        // ---------------- elementwise: L1 range + BCE mask ----------------
        float srv = 0.0f, smk = 0.0f;
        int base = (bid * 256 + tid) * 2;
#pragma unroll
        for (int u = 0; u < 2; ++u) {
            int i = base + u;
            float4 o4 = rv4[i];
            float4 x4 = lg4[i];
            float4 t4 = tg4[i];
            const float* op = &o4.x;
            const float* xp = &x4.x;
            const float* tp = &t4.x;
#pragma unroll
            for (int j = 0; j < 4; ++j) {
                float tv = tp[j];
                float ov = (tv == -1.0f) ? -1.0f : op[j];
                srv += fabsf(ov - tv);
                float tm = (tv > 0.0f) ? 1.0f : 0.0f;
                float xv = xp[j];
                smk += fmaxf(xv, 0.0f) - xv * tm + __logf(1.0f + __expf(-fabsf(xv)));
            }
        }
#pragma unroll
        for (int off = 32; off > 0; off >>= 1) {
            srv += __shfl_down(srv, off);
            smk += __shfl_down(smk, off);
        }
        if (lane == 0) { s1[wave] = srv; s2[wave] = smk; }
        __syncthreads();
        if (tid == 0) {
            st_agent(&ws[EW1 + bid], s1[0] + s1[1] + s1[2] + s1[3]);
            st_agent(&ws[EW2 + bid], s2[0] + s2[1] + s2[2] + s2[3]);
        }
    } else {
        // ------------- chamfer via MFMA: 64 queries x 4096 points per block -------------
        int cb = bid - EW_BLOCKS;            // 0..1280
        int dir = cb / (NBT * NQC);
        int rem = cb % (NBT * NQC);
        int bt = rem / NQC;
        int qc = rem % NQC;
        const float* P = dir ? TP : OP;      // queries
        const float* Q = dir ? OP : TP;      // references
        const float* Pb = P + (size_t)bt * NPTS * 3;
        const float* Qb = Q + (size_t)bt * NPTS * 3;

        int qrow = lane & 31;
        int wq = wave & 1;                   // query half (0: q0..31, 1: q32..63)
        int ph = wave >> 1;                  // point half (0: pts 0..2047, 1: 2048..4095)

        // A fragment: row = lane&31 -> query; k=(lane>>5)*8+i; data only in k=0..3.
        // Lanes >=32 (k=8..15) are ZERO in A, making B's k>=4 slots don't-care.
        int qidx = qc * QPB + wq * 32 + qrow;
        float qx = 0.0f, qy = 0.0f, qz = 0.0f;
        if (lane < 32) {
            const float* p = Pb + (size_t)qidx * 3;
            qx = p[0]; qy = p[1]; qz = p[2];
            nqlds[wq * 32 + qrow] = fmaf(qx, qx, fmaf(qy, qy, qz * qz));  // dup write benign
        }
        union { unsigned u[4]; h8 h; } ua;
        ua.u[0] = ua.u[1] = ua.u[2] = ua.u[3] = 0u;
        if (lane < 32) {
            ua.u[0] = pkh(-2.0f * qx, -2.0f * qy);
            ua.u[1] = pkh(-2.0f * qz, 1.0f);
        }
        h8 afrag = ua.h;

        // Stage ALL 4096 points as f16 (x,y | z,n); 16 points per thread, one barrier.
#pragma unroll
        for (int t = 0; t < 4; ++t) {
            int pt0 = t * 1024 + tid * 4;
            const f32x4* src = (const f32x4*)(Qb + (size_t)pt0 * 3);
            f32x4 c0 = src[0], c1 = src[1], c2 = src[2];
            float x0 = c0[0], y0 = c0[1], z0 = c0[2];
            float x1 = c0[3], y1 = c1[0], z1 = c1[1];
            float x2 = c1[2], y2 = c1[3], z2 = c2[0];
            float x3 = c2[1], y3 = c2[2], z3 = c2[3];
            float n0 = fmaf(x0, x0, fmaf(y0, y0, z0 * z0));
            float n1 = fmaf(x1, x1, fmaf(y1, y1, z1 * z1));
            float n2 = fmaf(x2, x2, fmaf(y2, y2, z2 * z2));
            float n3 = fmaf(x3, x3, fmaf(y3, y3, z3 * z3));
            uint4* dst = (uint4*)&pts[t * 1024 + tid * 4];
            dst[0] = make_uint4(pkh(x0, y0), pkh(z0, n0), pkh(x1, y1), pkh(z1, n1));
            dst[1] = make_uint4(pkh(x2, y2), pkh(z2, n2), pkh(x3, y3), pkh(z3, n3));
        }
        __syncthreads();

        const f32x16 zc = {0.0f, 0.0f, 0.0f, 0.0f, 0.0f, 0.0f, 0.0f, 0.0f,
                           0.0f, 0.0f, 0.0f, 0.0f, 0.0f, 0.0f, 0.0f, 0.0f};
        float vm[16];
#pragma unroll
        for (int r = 0; r < 16; ++r) vm[r] = INFINITY;

        const uint2* pb = pts + ph * 2048;
#pragma unroll 4
        for (int g = 0; g < 16; ++g) {       // 16 groups x 128 points
            uint2 b0 = pb[g * 128 + 0 * 32 + qrow];   // lanes>=32: same addr, broadcast
            uint2 b1 = pb[g * 128 + 1 * 32 + qrow];
            uint2 b2 = pb[g * 128 + 2 * 32 + qrow];
            uint2 b3 = pb[g * 128 + 3 * 32 + qrow];
            union { unsigned u[4]; h8 h; } ub0, ub1, ub2, ub3;
            ub0.u[0] = b0.x; ub0.u[1] = b0.y; ub0.u[2] = 0u; ub0.u[3] = 0u;
            ub1.u[0] = b1.x; ub1.u[1] = b1.y; ub1.u[2] = 0u; ub1.u[3] = 0u;
            ub2.u[0] = b2.x; ub2.u[1] = b2.y; ub2.u[2] = 0u; ub2.u[3] = 0u;
            ub3.u[0] = b3.x; ub3.u[1] = b3.y; ub3.u[2] = 0u; ub3.u[3] = 0u;
            f32x16 d0 = __builtin_amdgcn_mfma_f32_32x32x16_f16(afrag, ub0.h, zc, 0, 0, 0);
            f32x16 d1 = __builtin_amdgcn_mfma_f32_32x32x16_f16(afrag, ub1.h, zc, 0, 0, 0);
            f32x16 d2 = __builtin_amdgcn_mfma_f32_32x32x16_f16(afrag, ub2.h, zc, 0, 0, 0);
            f32x16 d3 = __builtin_amdgcn_mfma_f32_32x32x16_f16(afrag, ub3.h, zc, 0, 0, 0);
#pragma unroll
            for (int r = 0; r < 16; ++r) {
                float a = d0[r], c = d1[r];
                asm("v_min3_f32 %0, %0, %1, %2" : "+v"(vm[r]) : "v"(a), "v"(c));
            }
#pragma unroll
            for (int r = 0; r < 16; ++r) {
                float a = d2[r], c = d3[r];
                asm("v_min3_f32 %0, %0, %1, %2" : "+v"(vm[r]) : "v"(a), "v"(c));
            }
        }

        // column-min across each 32-lane half (rows split by lane>>5)
#pragma unroll
        for (int r = 0; r < 16; ++r) {
            float m = vm[r];
            m = fminf(m, __shfl_xor(m, 1));
            m = fminf(m, __shfl_xor(m, 2));
            m = fminf(m, __shfl_xor(m, 4));
            m = fminf(m, __shfl_xor(m, 8));
            m = fminf(m, __shfl_xor(m, 16));
            vm[r] = m;
        }
        if ((lane & 31) == 0) {
            int half = lane >> 5;
#pragma unroll
            for (int r = 0; r < 16; ++r) {
                int row = (r & 3) + 8 * (r >> 2) + 4 * half;
                qmin[ph][wq * 32 + row] = vm[r];
            }
        }
        __syncthreads();

        // combine point halves, add ||p||^2, sum 64 queries -> one partial
        if (wave == 0) {
            float m = fminf(qmin[0][lane], qmin[1][lane]) + nqlds[lane];
#pragma unroll
            for (int off = 32; off > 0; off >>= 1) m += __shfl_down(m, off);
            if (lane == 0) st_agent(&ws[cb], m);
        }
    }

    // ---------- fused finalize: last-arriving block reduces everything ----------
    __syncthreads();
    if (tid == 0) {
        unsigned old = __hip_atomic_fetch_add((unsigned*)(ws + CNT_IDX), 1u,
                                              __ATOMIC_ACQ_REL, __HIP_MEMORY_SCOPE_AGENT);
        // exactly one block per call satisfies this, for ANY initial counter value
        lastf = ((old % (unsigned)TOT_BLOCKS) == (unsigned)(TOT_BLOCKS - 1)) ? 1u : 0u;
    }
    __syncthreads();
    if (!lastf) return;

    // chamfer partials: 20 groups (dir*10+bt) of exactly 64
    for (int g = wave; g < 20; g += 4) {
        float s = ld_agent(&ws[g * 64 + lane]);
#pragma unroll
        for (int off = 32; off > 0; off >>= 1) s += __shfl_down(s, off);
        if (lane == 0) grp[g] = s;
    }

    // ew partials: 640 each
    float sa = 0.0f, sb = 0.0f;
    for (int i = tid; i < EW_BLOCKS; i += 256) {
        sa += ld_agent(&ws[EW1 + i]);
        sb += ld_agent(&ws[EW2 + i]);
    }
#pragma unroll
    for (int off = 32; off > 0; off >>= 1) {
        sa += __shfl_down(sa, off);
        sb += __shfl_down(sb, off);
    }
    if (lane == 0) { ra[wave] = sa; rb[wave] = sb; }
    __syncthreads();

    if (tid == 0) {
        const float inv_e = 1.0f / (float)NELEM;
        float loss_rv = (ra[0] + ra[1] + ra[2] + ra[3]) * inv_e;
        float loss_mask = (rb[0] + rb[1] + rb[2] + rb[3]) * inv_e;
        float cd_sum = 0.0f;
        for (int bt = 0; bt < NBT; ++bt) {
            float cd = (grp[bt] + grp[NBT + bt]) * (1.0f / NPTS);
            int b = bt / TT;
            int t = bt % TT;
            out[1 + t * BB + b] = cd;   // cd_tensor is [T,B]
            cd_sum += cd;
        }
        float loss_cd = cd_sum / (float)NBT;
        out[0] = loss_cd + loss_rv + loss_mask;  // weights all 1.0
        out[11] = loss_cd;
        out[12] = loss_rv;
        out[13] = loss_mask;
    }
}

extern "C" void kernel_launch(void* const* d_in, const int* in_sizes, int n_in,
                              void* d_out, int out_size, void* d_ws, size_t ws_size,
                              hipStream_t stream) {
    const float* output_rv = (const float*)d_in[0];
    const float* mask_logits = (const float*)d_in[1];
    const float* output_points = (const float*)d_in[2];
    const float* target_points = (const float*)d_in[3];
    const float* target_rv = (const float*)d_in[4];
    float* out = (float*)d_out;
    float* ws = (float*)d_ws;

    main_kernel<<<TOT_BLOCKS, 256, 0, stream>>>(
        (const float4*)output_rv, (const float4*)mask_logits,
        (const float4*)target_rv, output_points, target_points, ws, out);
}

// Round 17
// 30.389 us; speedup vs baseline: 1.3988x; 1.3988x over previous
//
#include <hip/hip_runtime.h>
#include <math.h>

// Problem constants (fixed by setup_inputs)
#define BB 2
#define TT 5
#define NPTS 4096
#define NBT (BB * TT)
#define NELEM (BB * TT * 64 * 2048)   // 1,310,720

#define EW_BLOCKS 640
// Chamfer: 2 dir x 10 bt x 64 qc = 1280 blocks, 64 queries each, all 4096 pts
#define CH_BLOCKS 1280
#define QPB 64
#define NQC 64

// ws layout (floats):
//   [0..1280)      chamfer partials, slot = dir*640 + bt*64 + qc
//   [1280..1920)   ew srv partials
//   [1920..2560)   ew smk partials
#define EW1 1280
#define EW2 1920

typedef _Float16 h8 __attribute__((ext_vector_type(8)));
typedef float f32x16 __attribute__((ext_vector_type(16)));
typedef float f32x4 __attribute__((ext_vector_type(4)));

__device__ inline unsigned pkh(float a, float b) {
    union { _Float16 h[2]; unsigned u; } c;
    c.h[0] = (_Float16)a;          // RNE conversion (absmax 4.9e-4 measured)
    c.h[1] = (_Float16)b;
    return c.u;
}

__global__ __launch_bounds__(256) void main_kernel(
        const float4* __restrict__ rv4,
        const float4* __restrict__ lg4,
        const float4* __restrict__ tg4,
        const float* __restrict__ OP,
        const float* __restrict__ TP,
        float* __restrict__ ws) {
    __shared__ __align__(16) uint2 pts[4096];   // (x,y)f16,(z,n)f16 per point, 32 KB
    __shared__ float nqlds[QPB];
    __shared__ float qmin[2][QPB];
    int bid = blockIdx.x;
    int tid = threadIdx.x;
    int lane = tid & 63;
    int wave = tid >> 6;

    if (bid < EW_BLOCKS) {
        // ---------------- elementwise: L1 range + BCE mask ----------------
        float srv = 0.0f, smk = 0.0f;
        int base = (bid * 256 + tid) * 2;
#pragma unroll
        for (int u = 0; u < 2; ++u) {
            int i = base + u;
            float4 o4 = rv4[i];
            float4 x4 = lg4[i];
            float4 t4 = tg4[i];
            const float* op = &o4.x;
            const float* xp = &x4.x;
            const float* tp = &t4.x;
#pragma unroll
            for (int j = 0; j < 4; ++j) {
                float tv = tp[j];
                float ov = (tv == -1.0f) ? -1.0f : op[j];
                srv += fabsf(ov - tv);
                float tm = (tv > 0.0f) ? 1.0f : 0.0f;
                float xv = xp[j];
                smk += fmaxf(xv, 0.0f) - xv * tm + __logf(1.0f + __expf(-fabsf(xv)));
            }
        }
#pragma unroll
        for (int off = 32; off > 0; off >>= 1) {
            srv += __shfl_down(srv, off);
            smk += __shfl_down(smk, off);
        }
        __shared__ float s1[4], s2[4];
        if (lane == 0) { s1[wave] = srv; s2[wave] = smk; }
        __syncthreads();
        if (tid == 0) {
            ws[EW1 + bid] = s1[0] + s1[1] + s1[2] + s1[3];
            ws[EW2 + bid] = s2[0] + s2[1] + s2[2] + s2[3];
        }
        return;
    }

    // ------------- chamfer via MFMA: one block = 64 queries x 4096 points -------------
    int cb = bid - EW_BLOCKS;            // 0..1280
    int dir = cb / (NBT * NQC);
    int rem = cb % (NBT * NQC);
    int bt = rem / NQC;
    int qc = rem % NQC;
    const float* P = dir ? TP : OP;      // queries
    const float* Q = dir ? OP : TP;      // references
    const float* Pb = P + (size_t)bt * NPTS * 3;
    const float* Qb = Q + (size_t)bt * NPTS * 3;

    int qrow = lane & 31;
    int wq = wave & 1;                   // query half (0: q0..31, 1: q32..63)
    int ph = wave >> 1;                  // point half (0: pts 0..2047, 1: 2048..4095)

    // A fragment: row = lane&31 -> query; k=(lane>>5)*8+i; data only in k=0..3.
    // Lanes >=32 (k=8..15) are ZERO in A, making B's k>=4 slots don't-care.
    int qidx = qc * QPB + wq * 32 + qrow;
    float qx = 0.0f, qy = 0.0f, qz = 0.0f;
    if (lane < 32) {
        const float* p = Pb + (size_t)qidx * 3;
        qx = p[0]; qy = p[1]; qz = p[2];
        nqlds[wq * 32 + qrow] = fmaf(qx, qx, fmaf(qy, qy, qz * qz));  // dup write (w0/w2), benign
    }
    union { unsigned u[4]; h8 h; } ua;
    ua.u[0] = ua.u[1] = ua.u[2] = ua.u[3] = 0u;
    if (lane < 32) {
        ua.u[0] = pkh(-2.0f * qx, -2.0f * qy);
        ua.u[1] = pkh(-2.0f * qz, 1.0f);
    }
    h8 afrag = ua.h;

    // Stage ALL 4096 points as f16 (x,y | z,n); 16 points per thread, one barrier.
#pragma unroll
    for (int t = 0; t < 4; ++t) {
        int pt0 = t * 1024 + tid * 4;
        const f32x4* src = (const f32x4*)(Qb + (size_t)pt0 * 3);
        f32x4 c0 = src[0], c1 = src[1], c2 = src[2];
        float x0 = c0[0], y0 = c0[1], z0 = c0[2];
        float x1 = c0[3], y1 = c1[0], z1 = c1[1];
        float x2 = c1[2], y2 = c1[3], z2 = c2[0];
        float x3 = c2[1], y3 = c2[2], z3 = c2[3];
        float n0 = fmaf(x0, x0, fmaf(y0, y0, z0 * z0));
        float n1 = fmaf(x1, x1, fmaf(y1, y1, z1 * z1));
        float n2 = fmaf(x2, x2, fmaf(y2, y2, z2 * z2));
        float n3 = fmaf(x3, x3, fmaf(y3, y3, z3 * z3));
        uint4* dst = (uint4*)&pts[t * 1024 + tid * 4];
        dst[0] = make_uint4(pkh(x0, y0), pkh(z0, n0), pkh(x1, y1), pkh(z1, n1));
        dst[1] = make_uint4(pkh(x2, y2), pkh(z2, n2), pkh(x3, y3), pkh(z3, n3));
    }
    __syncthreads();

    const f32x16 zc = {0.0f, 0.0f, 0.0f, 0.0f, 0.0f, 0.0f, 0.0f, 0.0f,
                       0.0f, 0.0f, 0.0f, 0.0f, 0.0f, 0.0f, 0.0f, 0.0f};
    float vm[16];
#pragma unroll
    for (int r = 0; r < 16; ++r) vm[r] = INFINITY;

    // B-fragment unions hoisted: upper k-slots zeroed ONCE (A's k>=4 coeffs are 0).
    union { unsigned u[4]; h8 h; } ub0, ub1, ub2, ub3;
    ub0.u[2] = ub0.u[3] = 0u;
    ub1.u[2] = ub1.u[3] = 0u;
    ub2.u[2] = ub2.u[3] = 0u;
    ub3.u[2] = ub3.u[3] = 0u;

    // One loop-invariant LDS base; all 64 reads at compile-time offsets (<16 KB).
    const uint2* pb = pts + ph * 2048 + qrow;
#pragma unroll
    for (int g = 0; g < 16; ++g) {       // FULL unroll: offsets fold to immediates
        uint2 b0 = pb[g * 128 + 0 * 32];          // lanes>=32: same addr, broadcast
        uint2 b1 = pb[g * 128 + 1 * 32];
        uint2 b2 = pb[g * 128 + 2 * 32];
        uint2 b3 = pb[g * 128 + 3 * 32];
        ub0.u[0] = b0.x; ub0.u[1] = b0.y;
        ub1.u[0] = b1.x; ub1.u[1] = b1.y;
        ub2.u[0] = b2.x; ub2.u[1] = b2.y;
        ub3.u[0] = b3.x; ub3.u[1] = b3.y;
        f32x16 d0 = __builtin_amdgcn_mfma_f32_32x32x16_f16(afrag, ub0.h, zc, 0, 0, 0);
        f32x16 d1 = __builtin_amdgcn_mfma_f32_32x32x16_f16(afrag, ub1.h, zc, 0, 0, 0);
        f32x16 d2 = __builtin_amdgcn_mfma_f32_32x32x16_f16(afrag, ub2.h, zc, 0, 0, 0);
        f32x16 d3 = __builtin_amdgcn_mfma_f32_32x32x16_f16(afrag, ub3.h, zc, 0, 0, 0);
#pragma unroll
        for (int r = 0; r < 16; ++r) {
            float a = d0[r], c = d1[r];
            asm("v_min3_f32 %0, %0, %1, %2" : "+v"(vm[r]) : "v"(a), "v"(c));
        }
#pragma unroll
        for (int r = 0; r < 16; ++r) {
            float a = d2[r], c = d3[r];
            asm("v_min3_f32 %0, %0, %1, %2" : "+v"(vm[r]) : "v"(a), "v"(c));
        }
    }

    // column-min across each 32-lane half (rows split by lane>>5)
#pragma unroll
    for (int r = 0; r < 16; ++r) {
        float m = vm[r];
        m = fminf(m, __shfl_xor(m, 1));
        m = fminf(m, __shfl_xor(m, 2));
        m = fminf(m, __shfl_xor(m, 4));
        m = fminf(m, __shfl_xor(m, 8));
        m = fminf(m, __shfl_xor(m, 16));
        vm[r] = m;
    }
    if ((lane & 31) == 0) {
        int half = lane >> 5;
#pragma unroll
        for (int r = 0; r < 16; ++r) {
            int row = (r & 3) + 8 * (r >> 2) + 4 * half;
            qmin[ph][wq * 32 + row] = vm[r];
        }
    }
    __syncthreads();

    // combine point halves, add ||p||^2, sum 64 queries -> one partial
    if (wave == 0) {
        float m = fminf(qmin[0][lane], qmin[1][lane]) + nqlds[lane];
#pragma unroll
        for (int off = 32; off > 0; off >>= 1) m += __shfl_down(m, off);
        if (lane == 0) ws[cb] = m;
    }
}

__global__ void finalize_kernel(const float* __restrict__ ws, float* __restrict__ out) {
    __shared__ float grp[20];
    __shared__ float ra[4], rb[4];
    int tid = threadIdx.x;
    int lane = tid & 63;
    int wave = tid >> 6;

    // chamfer partials: 20 groups (dir*10+bt) of exactly 64
    for (int g = wave; g < 20; g += 4) {
        float s = ws[g * 64 + lane];
#pragma unroll
        for (int off = 32; off > 0; off >>= 1) s += __shfl_down(s, off);
        if (lane == 0) grp[g] = s;
    }

    // ew partials: 640 each
    float sa = 0.0f, sb = 0.0f;
    for (int i = tid; i < EW_BLOCKS; i += 256) {
        sa += ws[EW1 + i];
        sb += ws[EW2 + i];
    }
#pragma unroll
    for (int off = 32; off > 0; off >>= 1) {
        sa += __shfl_down(sa, off);
        sb += __shfl_down(sb, off);
    }
    if (lane == 0) { ra[wave] = sa; rb[wave] = sb; }
    __syncthreads();

    if (tid == 0) {
        const float inv_e = 1.0f / (float)NELEM;
        float loss_rv = (ra[0] + ra[1] + ra[2] + ra[3]) * inv_e;
        float loss_mask = (rb[0] + rb[1] + rb[2] + rb[3]) * inv_e;
        float cd_sum = 0.0f;
        for (int bt = 0; bt < NBT; ++bt) {
            float cd = (grp[bt] + grp[NBT + bt]) * (1.0f / NPTS);
            int b = bt / TT;
            int t = bt % TT;
            out[1 + t * BB + b] = cd;   // cd_tensor is [T,B]
            cd_sum += cd;
        }
        float loss_cd = cd_sum / (float)NBT;
        out[0] = loss_cd + loss_rv + loss_mask;  // weights all 1.0
        out[11] = loss_cd;
        out[12] = loss_rv;
        out[13] = loss_mask;
    }
}

extern "C" void kernel_launch(void* const* d_in, const int* in_sizes, int n_in,
                              void* d_out, int out_size, void* d_ws, size_t ws_size,
                              hipStream_t stream) {
    const float* output_rv = (const float*)d_in[0];
    const float* mask_logits = (const float*)d_in[1];
    const float* output_points = (const float*)d_in[2];
    const float* target_points = (const float*)d_in[3];
    const float* target_rv = (const float*)d_in[4];
    float* out = (float*)d_out;
    float* ws = (float*)d_ws;

    main_kernel<<<EW_BLOCKS + CH_BLOCKS, 256, 0, stream>>>(
        (const float4*)output_rv, (const float4*)mask_logits,
        (const float4*)target_rv, output_points, target_points, ws);

    finalize_kernel<<<1, 256, 0, stream>>>(ws, out);
}